// Round 4
// baseline (2449.484 us; speedup 1.0000x reference)
//
#include <hip/hip_runtime.h>
#include <hip/hip_bf16.h>

// Problem constants (all fp32 I/O; bf16 only internally for MFMA)
#define BATCH 32
#define NTRAJ 512
#define LAT   256
#define HID   1024
#define TSTEPS 10
// Only the 512 trajectory rows per batch matter: the corrcoef rows evolve
// independently (f is row-wise) and are sliced away by the reference.
#define MTOT  (BATCH*NTRAJ)              // 16384
#define STATE_ELEMS ((size_t)MTOT*LAT)   // 4,194,304

typedef short bf16x8 __attribute__((ext_vector_type(8)));
typedef float f32x4  __attribute__((ext_vector_type(4)));

__device__ __forceinline__ unsigned short f2bfu(float f) {
    __hip_bfloat16 h = __float2bfloat16(f);
    unsigned short u; __builtin_memcpy(&u, &h, 2); return u;
}

__device__ __forceinline__ void async_copy16(const __hip_bfloat16* g, __hip_bfloat16* l) {
    __builtin_amdgcn_global_load_lds(
        (const __attribute__((address_space(1))) void*)g,
        (__attribute__((address_space(3))) void*)l,
        16, 0, 0);
}

// ---- W transpose + bf16 cast: dst[c][r] = bf16(src[r][c]) -----------------
__global__ void transpose_kernel(const float* __restrict__ src,
                                 __hip_bfloat16* __restrict__ dst,
                                 int rows, int cols) {
    int i = blockIdx.x * blockDim.x + threadIdx.x;
    if (i >= rows * cols) return;
    int c = i / rows;
    int r = i - c * rows;
    dst[i] = __float2bfloat16(src[(size_t)r * cols + c]);
}

// ---- init: first_point -> x (fp32 copy), xbf (bf16), out t=0 slice --------
__global__ void init_kernel(const float* __restrict__ fp,
                            float* __restrict__ x, __hip_bfloat16* __restrict__ xbf,
                            float* __restrict__ out) {
    size_t i4 = ((size_t)blockIdx.x * blockDim.x + threadIdx.x) * 4;  // < 4,194,304
    float4 v = *(const float4*)(fp + i4);
    *(float4*)(x + i4) = v;
    ushort4 p;
    p.x = f2bfu(v.x); p.y = f2bfu(v.y); p.z = f2bfu(v.z); p.w = f2bfu(v.w);
    *(ushort4*)((unsigned short*)xbf + i4) = p;
    size_t row = i4 >> 8;                  // b*512 + n
    int d = (int)(i4 & 255);
    *(float4*)(out + (row*TSTEPS + 0)*LAT + d) = v;
}

// ---------------- MFMA GEMM: C = A(MxK) * Bt(NxK)^T ------------------------
// m97-style async global->LDS staging (validated: rounds 2/3 bit-identical).
// EPI 0: C = bf16(tanh(acc + bias[n])) -> hidden
// EPI 1: C = fp32 acc -> k buffer
template<int EPI>
__global__ __launch_bounds__(256)
void gemm_bt_kernel(const __hip_bfloat16* __restrict__ A,
                    const __hip_bfloat16* __restrict__ Bt,
                    const float* __restrict__ bias,
                    void* __restrict__ Cout,
                    int N, int K) {
    __shared__ __align__(16) __hip_bfloat16 As[128*32];
    __shared__ __align__(16) __hip_bfloat16 Bs[128*32];
    const int tid  = threadIdx.x;
    const int lane = tid & 63;
    const int wave = tid >> 6;
    const int wm = wave >> 1, wn = wave & 1;
    const int q = lane >> 4, l16 = lane & 15;
    const int bm = blockIdx.x * 128;
    const int bn = blockIdx.y * 128;

    // staging: each wave issues 2 segments of 1KB (64 lanes x 16B) per matrix
    const int s0 = wave * 2, s1 = s0 + 1;
    const int lrow = lane >> 2;        // 0..15
    const int lcol = (lane & 3) * 8;   // 0,8,16,24
    const __hip_bfloat16* ga0 = A  + (size_t)(bm + s0*16 + lrow)*K + lcol;
    const __hip_bfloat16* ga1 = A  + (size_t)(bm + s1*16 + lrow)*K + lcol;
    const __hip_bfloat16* gb0 = Bt + (size_t)(bn + s0*16 + lrow)*K + lcol;
    const __hip_bfloat16* gb1 = Bt + (size_t)(bn + s1*16 + lrow)*K + lcol;
    __hip_bfloat16* la0 = As + s0*512;   // wave-uniform LDS base; HW: +lane*16B
    __hip_bfloat16* la1 = As + s1*512;
    __hip_bfloat16* lb0 = Bs + s0*512;
    __hip_bfloat16* lb1 = Bs + s1*512;

    f32x4 acc[4][4];
    #pragma unroll
    for (int i = 0; i < 4; ++i)
        #pragma unroll
        for (int j = 0; j < 4; ++j)
            acc[i][j] = (f32x4){0.f, 0.f, 0.f, 0.f};

    for (int k0 = 0; k0 < K; k0 += 32) {
        async_copy16(ga0 + k0, la0);
        async_copy16(ga1 + k0, la1);
        async_copy16(gb0 + k0, lb0);
        async_copy16(gb1 + k0, lb1);
        __syncthreads();   // compiler drains vmcnt before s_barrier
        bf16x8 af[4], bfr[4];
        #pragma unroll
        for (int mt = 0; mt < 4; ++mt)
            af[mt] = *(const bf16x8*)(As + ((wm*64 + mt*16 + l16)*32 + q*8));
        #pragma unroll
        for (int nt = 0; nt < 4; ++nt)
            bfr[nt] = *(const bf16x8*)(Bs + ((wn*64 + nt*16 + l16)*32 + q*8));
        #pragma unroll
        for (int mt = 0; mt < 4; ++mt)
            #pragma unroll
            for (int nt = 0; nt < 4; ++nt)
                acc[mt][nt] = __builtin_amdgcn_mfma_f32_16x16x32_bf16(
                                  af[mt], bfr[nt], acc[mt][nt], 0, 0, 0);
        __syncthreads();   // before next-tile staging overwrites LDS
    }

    // epilogue: D row=(q*4+r), col=l16 within each 16x16 tile
    if (EPI == 0) {
        __hip_bfloat16* H = (__hip_bfloat16*)Cout;
        #pragma unroll
        for (int nt = 0; nt < 4; ++nt) {
            int col = bn + wn*64 + nt*16 + l16;
            float bv = bias[col];
            #pragma unroll
            for (int mt = 0; mt < 4; ++mt) {
                int row0 = bm + wm*64 + mt*16 + q*4;
                #pragma unroll
                for (int r = 0; r < 4; ++r) {
                    float v = acc[mt][nt][r] + bv;
                    float e = __expf(2.f*v);
                    float th = 1.f - 2.f/(e + 1.f);   // tanh(v)
                    H[(size_t)(row0 + r)*N + col] = __float2bfloat16(th);
                }
            }
        }
    } else {
        float* Co = (float*)Cout;
        #pragma unroll
        for (int nt = 0; nt < 4; ++nt) {
            int col = bn + wn*64 + nt*16 + l16;
            #pragma unroll
            for (int mt = 0; mt < 4; ++mt) {
                int row0 = bm + wm*64 + mt*16 + q*4;
                #pragma unroll
                for (int r = 0; r < 4; ++r)
                    Co[(size_t)(row0 + r)*N + col] = acc[mt][nt][r];
            }
        }
    }
}

// ---------------- RK4 elementwise: xbf = bf16(x + c*dt*k); acc update ------
__global__ void prep_kernel(const float* __restrict__ x, const float* __restrict__ k,
                            float* __restrict__ acc, __hip_bfloat16* __restrict__ xbf,
                            const float* __restrict__ ts, int step,
                            float cmul, int accmode) {
    size_t i4 = ((size_t)blockIdx.x * blockDim.x + threadIdx.x) * 4;
    float dt = ts[step+1] - ts[step];
    float c = cmul * dt;
    float4 xv = *(const float4*)(x + i4);
    float4 kv = *(const float4*)(k + i4);
    if (accmode == 0) {
        *(float4*)(acc + i4) = kv;                       // acc = k1
    } else {
        float4 av = *(const float4*)(acc + i4);          // acc += 2*k
        av.x += 2.f*kv.x; av.y += 2.f*kv.y; av.z += 2.f*kv.z; av.w += 2.f*kv.w;
        *(float4*)(acc + i4) = av;
    }
    ushort4 p;
    p.x = f2bfu(xv.x + c*kv.x);
    p.y = f2bfu(xv.y + c*kv.y);
    p.z = f2bfu(xv.z + c*kv.z);
    p.w = f2bfu(xv.w + c*kv.w);
    *(ushort4*)((unsigned short*)xbf + i4) = p;
}

// ---- RK4 combine: x += dt/6*(acc + k4); emit fp32 output slice ------------
__global__ void combine_kernel(float* __restrict__ x, const float* __restrict__ acc,
                               const float* __restrict__ k4,
                               __hip_bfloat16* __restrict__ xbf,
                               float* __restrict__ out,
                               const float* __restrict__ ts, int step) {
    size_t i4 = ((size_t)blockIdx.x * blockDim.x + threadIdx.x) * 4;
    float dt = ts[step+1] - ts[step];
    float w = dt * (1.f/6.f);
    float4 xv = *(const float4*)(x + i4);
    float4 av = *(const float4*)(acc + i4);
    float4 kv = *(const float4*)(k4 + i4);
    xv.x += w*(av.x + kv.x);
    xv.y += w*(av.y + kv.y);
    xv.z += w*(av.z + kv.z);
    xv.w += w*(av.w + kv.w);
    *(float4*)(x + i4) = xv;
    ushort4 p;
    p.x = f2bfu(xv.x); p.y = f2bfu(xv.y); p.z = f2bfu(xv.z); p.w = f2bfu(xv.w);
    *(ushort4*)((unsigned short*)xbf + i4) = p;
    size_t row = i4 >> 8;          // b*512 + n  (all rows are output rows)
    int d = (int)(i4 & 255);
    *(float4*)(out + (row*TSTEPS + (step+1))*LAT + d) = xv;
}

extern "C" void kernel_launch(void* const* d_in, const int* in_sizes, int n_in,
                              void* d_out, int out_size, void* d_ws, size_t ws_size,
                              hipStream_t stream) {
    const float* fp = (const float*)d_in[0];
    const float* ts = (const float*)d_in[1];
    const float* W1 = (const float*)d_in[2];
    const float* b1 = (const float*)d_in[3];
    const float* W2 = (const float*)d_in[4];
    float* out = (float*)d_out;

    char* ws = (char*)d_ws;
    size_t off = 0;
    auto alloc = [&](size_t bytes) { void* p = ws + off; off += (bytes + 255) & ~(size_t)255; return p; };
    float*          x      = (float*)         alloc(STATE_ELEMS * 4);          // 16.8 MB
    __hip_bfloat16* xbf    = (__hip_bfloat16*)alloc(STATE_ELEMS * 2);          //  8.4 MB
    float*          kcur   = (float*)         alloc(STATE_ELEMS * 4);          // 16.8 MB
    float*          acc    = (float*)         alloc(STATE_ELEMS * 4);          // 16.8 MB
    __hip_bfloat16* W1t    = (__hip_bfloat16*)alloc((size_t)LAT * HID * 2);    //  0.5 MB
    __hip_bfloat16* W2t    = (__hip_bfloat16*)alloc((size_t)HID * LAT * 2);    //  0.5 MB
    size_t base = off;
    __hip_bfloat16* hidden = (__hip_bfloat16*)alloc((size_t)MTOT * HID * 2);   // 33.6 MB

    // hidden-chunk fallback if the workspace is small
    int rows_cap = MTOT;
    if (ws_size && ws_size < off) {
        size_t avail = (ws_size > base) ? (ws_size - base) : 0;
        size_t cap = avail / ((size_t)HID * 2);
        rows_cap = (int)((cap / 128) * 128);
        if (rows_cap < 128) rows_cap = 128;     // last resort
        if (rows_cap > MTOT) rows_cap = MTOT;
    }

    // --- setup ---
    transpose_kernel<<<(LAT*HID + 255)/256, 256, 0, stream>>>(W1, W1t, LAT, HID);
    transpose_kernel<<<(HID*LAT + 255)/256, 256, 0, stream>>>(W2, W2t, HID, LAT);
    init_kernel<<<(int)(STATE_ELEMS/4/256), 256, 0, stream>>>(fp, x, xbf, out);

    const int ew_blocks = (int)(STATE_ELEMS / 4 / 256);   // 4096, exact

    auto eval_f = [&](void) {   // kcur = f(xbf) ; hidden is scratch
        for (int r0 = 0; r0 < MTOT; r0 += rows_cap) {
            int rm = (r0 + rows_cap <= MTOT) ? rows_cap : (MTOT - r0);
            dim3 g1(rm/128, HID/128);   // x8
            dim3 g2(rm/128, LAT/128);   // x2
            gemm_bt_kernel<0><<<g1, 256, 0, stream>>>(
                xbf + (size_t)r0*LAT, W1t, b1, hidden, HID, LAT);
            gemm_bt_kernel<1><<<g2, 256, 0, stream>>>(
                hidden, W2t, nullptr, kcur + (size_t)r0*LAT, LAT, HID);
        }
    };

    for (int step = 0; step < TSTEPS - 1; ++step) {
        eval_f();   // k1 = f(x)
        prep_kernel<<<ew_blocks, 256, 0, stream>>>(x, kcur, acc, xbf, ts, step, 0.5f, 0);
        eval_f();   // k2 = f(x + dt/2 k1)
        prep_kernel<<<ew_blocks, 256, 0, stream>>>(x, kcur, acc, xbf, ts, step, 0.5f, 1);
        eval_f();   // k3 = f(x + dt/2 k2)
        prep_kernel<<<ew_blocks, 256, 0, stream>>>(x, kcur, acc, xbf, ts, step, 1.0f, 1);
        eval_f();   // k4 = f(x + dt k3)
        combine_kernel<<<ew_blocks, 256, 0, stream>>>(x, acc, kcur, xbf, out, ts, step);
    }
}

// Round 5
// 2393.033 us; speedup vs baseline: 1.0236x; 1.0236x over previous
//
#include <hip/hip_runtime.h>
#include <hip/hip_bf16.h>

// Problem constants (fp32 I/O; bf16 internally for MFMA)
#define BATCH 32
#define NTRAJ 512
#define LAT   256
#define HID   1024
#define TSTEPS 10
// Only the 512 trajectory rows per batch matter: the corrcoef rows evolve
// independently (f is row-wise) and are sliced away by the reference.
#define MTOT  (BATCH*NTRAJ)              // 16384
#define STATE_ELEMS ((size_t)MTOT*LAT)   // 4,194,304

typedef short bf16x8 __attribute__((ext_vector_type(8)));
typedef float f32x4  __attribute__((ext_vector_type(4)));

__device__ __forceinline__ unsigned short f2bfu(float f) {
    __hip_bfloat16 h = __float2bfloat16(f);
    unsigned short u; __builtin_memcpy(&u, &h, 2); return u;
}

__device__ __forceinline__ void async_copy16(const __hip_bfloat16* g, __hip_bfloat16* l) {
    __builtin_amdgcn_global_load_lds(
        (const __attribute__((address_space(1))) void*)g,
        (__attribute__((address_space(3))) void*)l,
        16, 0, 0);
}

// ---- W transpose + bf16 cast: dst[c][r] = bf16(src[r][c]) -----------------
__global__ void transpose_kernel(const float* __restrict__ src,
                                 __hip_bfloat16* __restrict__ dst,
                                 int rows, int cols) {
    int i = blockIdx.x * blockDim.x + threadIdx.x;
    if (i >= rows * cols) return;
    int c = i / rows;
    int r = i - c * rows;
    dst[i] = __float2bfloat16(src[(size_t)r * cols + c]);
}

// ---- init: first_point -> x (fp32 copy), xbf (bf16), out t=0 slice --------
__global__ void init_kernel(const float* __restrict__ fp,
                            float* __restrict__ x, __hip_bfloat16* __restrict__ xbf,
                            float* __restrict__ out) {
    size_t i4 = ((size_t)blockIdx.x * blockDim.x + threadIdx.x) * 4;  // < 4,194,304
    float4 v = *(const float4*)(fp + i4);
    *(float4*)(x + i4) = v;
    ushort4 p;
    p.x = f2bfu(v.x); p.y = f2bfu(v.y); p.z = f2bfu(v.z); p.w = f2bfu(v.w);
    *(ushort4*)((unsigned short*)xbf + i4) = p;
    size_t row = i4 >> 8;                  // b*512 + n
    int d = (int)(i4 & 255);
    *(float4*)(out + (row*TSTEPS + 0)*LAT + d) = v;
}

// ---------------- GEMM1: hidden = bf16(tanh(xbf @ W1 + b1)) ----------------
// 128x128 tile, m97-style async staging (validated rounds 2-4).
__global__ __launch_bounds__(256)
void gemm1_kernel(const __hip_bfloat16* __restrict__ A,    // MTOT x LAT
                  const __hip_bfloat16* __restrict__ Bt,   // HID x LAT (W1t)
                  const float* __restrict__ bias,
                  __hip_bfloat16* __restrict__ H) {        // MTOT x HID
    __shared__ __align__(16) __hip_bfloat16 As[128*32];
    __shared__ __align__(16) __hip_bfloat16 Bs[128*32];
    const int tid  = threadIdx.x;
    const int lane = tid & 63;
    const int wave = tid >> 6;
    const int wm = wave >> 1, wn = wave & 1;
    const int q = lane >> 4, l16 = lane & 15;
    const int bm = blockIdx.x * 128;
    const int bn = blockIdx.y * 128;

    const int s0 = wave * 2, s1 = s0 + 1;
    const int lrow = lane >> 2;        // 0..15
    const int lcol = (lane & 3) * 8;   // 0,8,16,24
    const __hip_bfloat16* ga0 = A  + (size_t)(bm + s0*16 + lrow)*LAT + lcol;
    const __hip_bfloat16* ga1 = A  + (size_t)(bm + s1*16 + lrow)*LAT + lcol;
    const __hip_bfloat16* gb0 = Bt + (size_t)(bn + s0*16 + lrow)*LAT + lcol;
    const __hip_bfloat16* gb1 = Bt + (size_t)(bn + s1*16 + lrow)*LAT + lcol;
    __hip_bfloat16* la0 = As + s0*512;   // wave-uniform base; HW adds lane*16B
    __hip_bfloat16* la1 = As + s1*512;
    __hip_bfloat16* lb0 = Bs + s0*512;
    __hip_bfloat16* lb1 = Bs + s1*512;

    f32x4 acc[4][4];
    #pragma unroll
    for (int i = 0; i < 4; ++i)
        #pragma unroll
        for (int j = 0; j < 4; ++j)
            acc[i][j] = (f32x4){0.f, 0.f, 0.f, 0.f};

    for (int k0 = 0; k0 < LAT; k0 += 32) {
        async_copy16(ga0 + k0, la0);
        async_copy16(ga1 + k0, la1);
        async_copy16(gb0 + k0, lb0);
        async_copy16(gb1 + k0, lb1);
        __syncthreads();
        bf16x8 af[4], bfr[4];
        #pragma unroll
        for (int mt = 0; mt < 4; ++mt)
            af[mt] = *(const bf16x8*)(As + ((wm*64 + mt*16 + l16)*32 + q*8));
        #pragma unroll
        for (int nt = 0; nt < 4; ++nt)
            bfr[nt] = *(const bf16x8*)(Bs + ((wn*64 + nt*16 + l16)*32 + q*8));
        #pragma unroll
        for (int mt = 0; mt < 4; ++mt)
            #pragma unroll
            for (int nt = 0; nt < 4; ++nt)
                acc[mt][nt] = __builtin_amdgcn_mfma_f32_16x16x32_bf16(
                                  af[mt], bfr[nt], acc[mt][nt], 0, 0, 0);
        __syncthreads();
    }

    // epilogue: D row=(q*4+r), col=l16 in each 16x16 tile
    #pragma unroll
    for (int nt = 0; nt < 4; ++nt) {
        int col = bn + wn*64 + nt*16 + l16;
        float bv = bias[col];
        #pragma unroll
        for (int mt = 0; mt < 4; ++mt) {
            int row0 = bm + wm*64 + mt*16 + q*4;
            #pragma unroll
            for (int r = 0; r < 4; ++r) {
                float v = acc[mt][nt][r] + bv;
                float e = __expf(2.f*v);
                float th = 1.f - 2.f/(e + 1.f);   // tanh(v)
                H[(size_t)(row0 + r)*HID + col] = __float2bfloat16(th);
            }
        }
    }
}

// ------- GEMM2 + fused RK4 stage: k = hidden @ W2, applied in epilogue -----
// Tile 64 x 256 (full N => hidden read exactly once), grid MTOT/64 = 256.
// 4 waves; wave w owns cols [w*64, w*64+64), all 64 rows => acc[4][4].
// MODE 0: acc = k;      xbf = bf16(x + 0.5*dt*k)
// MODE 1: acc += 2k;    xbf = bf16(x + 0.5*dt*k)
// MODE 2: acc += 2k;    xbf = bf16(x + dt*k)
// MODE 3: x += dt/6*(acc + k); xbf = bf16(x); out[:,step+1,:] = x
template<int MODE>
__global__ __launch_bounds__(256)
void gemm2_rk_kernel(const __hip_bfloat16* __restrict__ A,    // hidden MTOT x HID
                     const __hip_bfloat16* __restrict__ Bt,   // W2t LAT x HID
                     float* __restrict__ x,
                     float* __restrict__ acc_g,
                     __hip_bfloat16* __restrict__ xbf,
                     float* __restrict__ out,
                     const float* __restrict__ ts, int step) {
    __shared__ __align__(16) __hip_bfloat16 As[64*32];    //  4 KB
    __shared__ __align__(16) __hip_bfloat16 Bs[256*32];   // 16 KB
    const int tid  = threadIdx.x;
    const int lane = tid & 63;
    const int wave = tid >> 6;            // 0..3
    const int q = lane >> 4, l16 = lane & 15;
    const int bm = blockIdx.x * 64;

    // staging: A = 4 segs (wave w does seg w); B = 16 segs (wave w does w*4+i)
    const int lrow = lane >> 2;           // 0..15
    const int lcol = (lane & 3) * 8;      // 0,8,16,24
    const __hip_bfloat16* gA = A + (size_t)(bm + wave*16 + lrow)*HID + lcol;
    __hip_bfloat16* lA = As + wave*512;
    const __hip_bfloat16* gB[4];
    __hip_bfloat16* lB[4];
    #pragma unroll
    for (int i = 0; i < 4; ++i) {
        int sb = wave*4 + i;
        gB[i] = Bt + (size_t)(sb*16 + lrow)*HID + lcol;
        lB[i] = Bs + sb*512;
    }

    f32x4 acc[4][4];   // [row-tile mt][col-tile nt]
    #pragma unroll
    for (int i = 0; i < 4; ++i)
        #pragma unroll
        for (int j = 0; j < 4; ++j)
            acc[i][j] = (f32x4){0.f, 0.f, 0.f, 0.f};

    for (int k0 = 0; k0 < HID; k0 += 32) {
        async_copy16(gA + k0, lA);
        #pragma unroll
        for (int i = 0; i < 4; ++i)
            async_copy16(gB[i] + k0, lB[i]);
        __syncthreads();
        bf16x8 af[4], bfr[4];
        #pragma unroll
        for (int mt = 0; mt < 4; ++mt)
            af[mt] = *(const bf16x8*)(As + ((mt*16 + l16)*32 + q*8));
        #pragma unroll
        for (int nt = 0; nt < 4; ++nt)
            bfr[nt] = *(const bf16x8*)(Bs + ((wave*64 + nt*16 + l16)*32 + q*8));
        #pragma unroll
        for (int mt = 0; mt < 4; ++mt)
            #pragma unroll
            for (int nt = 0; nt < 4; ++nt)
                acc[mt][nt] = __builtin_amdgcn_mfma_f32_16x16x32_bf16(
                                  af[mt], bfr[nt], acc[mt][nt], 0, 0, 0);
        __syncthreads();
    }

    // fused RK4 epilogue; D row=(q*4+r), col=l16 per 16x16 tile
    float dt = ts[step+1] - ts[step];
    float c = (MODE == 2) ? dt : 0.5f*dt;
    float w6 = dt * (1.f/6.f);
    #pragma unroll
    for (int mt = 0; mt < 4; ++mt) {
        #pragma unroll
        for (int nt = 0; nt < 4; ++nt) {
            int col = wave*64 + nt*16 + l16;
            int row0 = bm + mt*16 + q*4;
            #pragma unroll
            for (int r = 0; r < 4; ++r) {
                size_t idx = (size_t)(row0 + r)*LAT + col;
                float kv = acc[mt][nt][r];
                if (MODE == 0) {
                    acc_g[idx] = kv;
                    xbf[idx] = __float2bfloat16(x[idx] + c*kv);
                } else if (MODE == 1 || MODE == 2) {
                    acc_g[idx] += 2.f*kv;
                    xbf[idx] = __float2bfloat16(x[idx] + c*kv);
                } else {
                    float xn = x[idx] + w6*(acc_g[idx] + kv);
                    x[idx] = xn;
                    xbf[idx] = __float2bfloat16(xn);
                    size_t row = (size_t)(row0 + r);
                    out[(row*TSTEPS + (step+1))*LAT + col] = xn;
                }
            }
        }
    }
}

extern "C" void kernel_launch(void* const* d_in, const int* in_sizes, int n_in,
                              void* d_out, int out_size, void* d_ws, size_t ws_size,
                              hipStream_t stream) {
    const float* fp = (const float*)d_in[0];
    const float* ts = (const float*)d_in[1];
    const float* W1 = (const float*)d_in[2];
    const float* b1 = (const float*)d_in[3];
    const float* W2 = (const float*)d_in[4];
    float* out = (float*)d_out;

    char* ws = (char*)d_ws;
    size_t off = 0;
    auto alloc = [&](size_t bytes) { void* p = ws + off; off += (bytes + 255) & ~(size_t)255; return p; };
    float*          x      = (float*)         alloc(STATE_ELEMS * 4);          // 16.8 MB
    __hip_bfloat16* xbf    = (__hip_bfloat16*)alloc(STATE_ELEMS * 2);          //  8.4 MB
    float*          acc    = (float*)         alloc(STATE_ELEMS * 4);          // 16.8 MB
    __hip_bfloat16* W1t    = (__hip_bfloat16*)alloc((size_t)LAT * HID * 2);    //  0.5 MB
    __hip_bfloat16* W2t    = (__hip_bfloat16*)alloc((size_t)HID * LAT * 2);    //  0.5 MB
    __hip_bfloat16* hidden = (__hip_bfloat16*)alloc((size_t)MTOT * HID * 2);   // 33.6 MB
    (void)off; (void)ws_size;   // round 4 ran with ~93 MB demand; this is ~77 MB

    // --- setup ---
    transpose_kernel<<<(LAT*HID + 255)/256, 256, 0, stream>>>(W1, W1t, LAT, HID);
    transpose_kernel<<<(HID*LAT + 255)/256, 256, 0, stream>>>(W2, W2t, HID, LAT);
    init_kernel<<<(int)(STATE_ELEMS/4/256), 256, 0, stream>>>(fp, x, xbf, out);

    dim3 g1(MTOT/128, HID/128);   // 128 x 8 = 1024 blocks
    const int g2 = MTOT/64;       // 256 blocks

    for (int step = 0; step < TSTEPS - 1; ++step) {
        gemm1_kernel<<<g1, 256, 0, stream>>>(xbf, W1t, b1, hidden);
        gemm2_rk_kernel<0><<<g2, 256, 0, stream>>>(hidden, W2t, x, acc, xbf, nullptr, ts, step);
        gemm1_kernel<<<g1, 256, 0, stream>>>(xbf, W1t, b1, hidden);
        gemm2_rk_kernel<1><<<g2, 256, 0, stream>>>(hidden, W2t, x, acc, xbf, nullptr, ts, step);
        gemm1_kernel<<<g1, 256, 0, stream>>>(xbf, W1t, b1, hidden);
        gemm2_rk_kernel<2><<<g2, 256, 0, stream>>>(hidden, W2t, x, acc, xbf, nullptr, ts, step);
        gemm1_kernel<<<g1, 256, 0, stream>>>(xbf, W1t, b1, hidden);
        gemm2_rk_kernel<3><<<g2, 256, 0, stream>>>(hidden, W2t, x, acc, xbf, out, ts, step);
    }
}